// Round 18
// baseline (197.849 us; speedup 1.0000x reference)
//
#include <hip/hip_runtime.h>
#include <math.h>

#define B_ 2
#define S_ 2048
#define D_ 1024
#define H_ 16
#define DK_ 64
#define M_ (B_*S_)   // 4096

typedef __attribute__((ext_vector_type(8))) _Float16 f16x8;
typedef __attribute__((ext_vector_type(4))) _Float16 f16x4;
typedef __attribute__((ext_vector_type(2))) __fp16 fp16x2;
typedef __attribute__((ext_vector_type(4))) float f32x4;
typedef __attribute__((ext_vector_type(4))) unsigned u32x4;

#define MFMA16(a,b,c) __builtin_amdgcn_mfma_f32_16x16x32_f16((a),(b),(c),0,0,0)

__device__ __forceinline__ void gload16(const void* g, void* l) {
    __builtin_amdgcn_global_load_lds(
        (const __attribute__((address_space(1))) unsigned int*)g,
        (__attribute__((address_space(3))) unsigned int*)l, 16, 0, 0);
}

// ---- X+W split (blocks 0..8191) + mask bit-pack (blocks 8192..40959) ---------
__global__ __launch_bounds__(256)
void splitmask(const float* __restrict__ query, const float* __restrict__ key_,
               const float* __restrict__ value,
               const float* __restrict__ Wq, const float* __restrict__ Wk,
               const float* __restrict__ Wv, const float* __restrict__ Wo,
               const int* __restrict__ mask, unsigned long long* __restrict__ mbits,
               _Float16* __restrict__ Xhq, _Float16* __restrict__ Xlq,
               _Float16* __restrict__ Xhk, _Float16* __restrict__ Xlk,
               _Float16* __restrict__ Xhv,
               _Float16* __restrict__ hq, _Float16* __restrict__ lq,
               _Float16* __restrict__ hk, _Float16* __restrict__ lk,
               _Float16* __restrict__ hv, _Float16* __restrict__ ho)
{
    if (blockIdx.x >= 8192) {
        int wid  = (blockIdx.x - 8192) * 4 + (threadIdx.x >> 6);
        int lane = threadIdx.x & 63;
        int v = mask[(size_t)wid * 64 + lane];
        unsigned long long bal = __ballot(v != 0);
        if (lane == 0) mbits[wid] = bal;
        return;
    }
    int t = blockIdx.x * 256 + threadIdx.x;   // 2M threads, 8 elems each
    int region = t >> 19;                     // 0=q 1=k 2=v 3=weights
    int u = t & 524287;
    const float* src; _Float16* dhi; _Float16* dlo; size_t e;
    if (region < 3) {
        e = (size_t)u * 8;
        src = (region == 0) ? query : (region == 1) ? key_ : value;
        dhi = (region == 0) ? Xhq : (region == 1) ? Xhk : Xhv;
        dlo = (region == 0) ? Xlq : (region == 1) ? Xlk : nullptr;
    } else {
        int mi = u >> 17;
        e = (size_t)(u & 131071) * 8;
        src = (mi == 0) ? Wq : (mi == 1) ? Wk : (mi == 2) ? Wv : Wo;
        dhi = (mi == 0) ? hq : (mi == 1) ? hk : (mi == 2) ? hv : ho;
        dlo = (mi == 0) ? lq : (mi == 1) ? lk : nullptr;
    }
    float4 a = *(const float4*)&src[e];
    float4 b = *(const float4*)&src[e + 4];
    float v[8] = {a.x, a.y, a.z, a.w, b.x, b.y, b.z, b.w};
    f16x8 hi, lo;
    #pragma unroll
    for (int j = 0; j < 8; ++j) {
        float s = v[j] * 64.f;                // pow2 scale keeps lo out of denorms
        _Float16 h = (_Float16)s;
        hi[j] = h; lo[j] = (_Float16)(s - (float)h);
    }
    *(f16x8*)&dhi[e] = hi;
    if (dlo) *(f16x8*)&dlo[e] = lo;
}

// ---------------- GEMM body: dbuf prefetch, all-gload16 staging ---------------
template<int NPROD, int OUT_MODE>
__device__ __forceinline__
void gemm_body2(char* smem, const _Float16* __restrict__ Ah,
                const _Float16* __restrict__ Al,
                const _Float16* __restrict__ Bh, const _Float16* __restrict__ Bl,
                const float* __restrict__ bias, void* __restrict__ outp, int gid)
{
    constexpr int BUFSZ = (NPROD == 3) ? 32768 : 16384;
    const int tid  = threadIdx.x;
    const int lane = tid & 63, w = tid >> 6;
    const int lx   = lane & 15, lg = lane >> 4;
    const int wm   = w >> 1, wn = w & 1;

    int nid = (gid & 7) * 32 + (gid >> 3);    // XCD-chunked swizzle
    const int colBase = (nid & 7) * 128;
    const int rowBase = (nid >> 3) * 128;

    const int sRow = (lane >> 2);
    const int sChk = (lane & 3) ^ ((lane >> 2) & 3);

    auto STAGE = [&](int buf, int k0) {
        char* base = smem + buf * BUFSZ;
        #pragma unroll
        for (int ii = 0; ii < 2; ++ii) {
            int i = w * 2 + ii;
            int r = i * 16 + sRow;
            gload16(Ah + (size_t)(rowBase + r) * D_ + k0 + sChk * 8, base + i * 1024);
            gload16(Bh + (size_t)(colBase + r) * D_ + k0 + sChk * 8, base + 8192 + i * 1024);
            if (NPROD == 3) {
                gload16(Al + (size_t)(rowBase + r) * D_ + k0 + sChk * 8, base + 16384 + i * 1024);
                gload16(Bl + (size_t)(colBase + r) * D_ + k0 + sChk * 8, base + 24576 + i * 1024);
            }
        }
    };

    f32x4 acc[4][4];
    #pragma unroll
    for (int i = 0; i < 4; ++i)
        #pragma unroll
        for (int j = 0; j < 4; ++j) acc[i][j] = (f32x4){0.f, 0.f, 0.f, 0.f};

    STAGE(0, 0);
    __syncthreads();
    int cur = 0;
    for (int k0 = 0; k0 < D_; k0 += 32) {
        if (k0 + 32 < D_) STAGE(cur ^ 1, k0 + 32);
        char* base = smem + cur * BUFSZ;
        _Float16* AhS = (_Float16*)base;
        _Float16* BhS = (_Float16*)(base + 8192);
        _Float16* AlS = (_Float16*)(base + 16384);
        _Float16* BlS = (_Float16*)(base + 24576);

        f16x8 bh[4], bl[4];
        #pragma unroll
        for (int fj = 0; fj < 4; ++fj) {
            int brow = wn * 64 + fj * 16 + lx;
            bh[fj] = *(const f16x8*)((char*)BhS + brow * 64 + 16 * (lg ^ (brow & 3)));
            if (NPROD == 3)
                bl[fj] = *(const f16x8*)((char*)BlS + brow * 64 + 16 * (lg ^ (brow & 3)));
        }
        #pragma unroll
        for (int fi = 0; fi < 4; ++fi) {
            int arow = wm * 64 + fi * 16 + lx;
            f16x8 ah = *(const f16x8*)((char*)AhS + arow * 64 + 16 * (lg ^ (arow & 3)));
            f16x8 al;
            if (NPROD == 3)
                al = *(const f16x8*)((char*)AlS + arow * 64 + 16 * (lg ^ (arow & 3)));
            #pragma unroll
            for (int fj = 0; fj < 4; ++fj) {
                acc[fi][fj] = MFMA16(ah, bh[fj], acc[fi][fj]);
                if (NPROD == 3) {
                    acc[fi][fj] = MFMA16(ah, bl[fj], acc[fi][fj]);
                    acc[fi][fj] = MFMA16(al, bh[fj], acc[fi][fj]);
                }
            }
        }
        __syncthreads();
        cur ^= 1;
    }

    constexpr float INV = 1.f / 4096.f;
    #pragma unroll
    for (int fi = 0; fi < 4; ++fi) {
        #pragma unroll
        for (int fj = 0; fj < 4; ++fj) {
            int n = colBase + wn * 64 + fj * 16 + lx;
            float bv = bias[n];
            if (OUT_MODE == 1) {
                _Float16* Ohi = (_Float16*)outp;
                _Float16* Olo = Ohi + (size_t)M_ * D_;
                int hh = n >> 6, d = n & 63;
                #pragma unroll
                for (int rr = 0; rr < 4; ++rr) {
                    int m = rowBase + wm * 64 + fi * 16 + lg * 4 + rr;
                    int bb = m >> 11, s = m & 2047;
                    float val = acc[fi][fj][rr] * INV + bv;
                    _Float16 hv = (_Float16)val;
                    size_t o = (((size_t)bb * H_ + hh) * S_ + s) * DK_ + d;
                    Ohi[o] = hv;
                    Olo[o] = (_Float16)(val - (float)hv);
                }
            } else {
                _Float16* Vt = (_Float16*)outp;
                int hh = n >> 6, d = n & 63;
                int m0 = rowBase + wm * 64 + fi * 16 + lg * 4;
                int bb = m0 >> 11, s = m0 & 2047;
                f16x4 pk;
                #pragma unroll
                for (int rr = 0; rr < 4; ++rr)
                    pk[rr] = (_Float16)(acc[fi][fj][rr] * INV + bv);
                *(f16x4*)&Vt[(((size_t)bb * H_ + hh) * DK_ + d) * S_ + s] = pk;
            }
        }
    }
}

// ---------------- merged Q/K/V projection: 768 blocks --------------------------
__global__ __launch_bounds__(256)
void proj3(const _Float16* __restrict__ Xhq, const _Float16* __restrict__ Xlq,
           const _Float16* __restrict__ Xhk, const _Float16* __restrict__ Xlk,
           const _Float16* __restrict__ Xhv,
           const _Float16* __restrict__ WhiQ, const _Float16* __restrict__ WloQ,
           const _Float16* __restrict__ WhiK, const _Float16* __restrict__ WloK,
           const _Float16* __restrict__ WhiV,
           const float* __restrict__ bq, const float* __restrict__ bk,
           const float* __restrict__ bv,
           _Float16* __restrict__ Qhi, _Float16* __restrict__ Khi,
           _Float16* __restrict__ VtW)
{
    extern __shared__ char smem[];
    int mode = blockIdx.x >> 8;
    int gid  = blockIdx.x & 255;
    if (mode == 0)
        gemm_body2<3, 1>(smem, Xhq, Xlq, WhiQ, WloQ, bq, Qhi, gid);
    else if (mode == 1)
        gemm_body2<3, 1>(smem, Xhk, Xlk, WhiK, WloK, bk, Khi, gid);
    else
        gemm_body2<1, 2>(smem, Xhv, nullptr, WhiV, nullptr, bv, VtW, gid);
}

// ---------------- O-proj GEMM: 64x128 tile, dbuf gload16 both operands --------
__global__ __launch_bounds__(256)
void gemm64(const _Float16* __restrict__ Ap, const _Float16* __restrict__ Bhi,
            const float* __restrict__ bias, float* __restrict__ out)
{
    __shared__ __attribute__((aligned(16))) char smem[24576];

    const int tid  = threadIdx.x;
    const int lane = tid & 63, w = tid >> 6;
    const int lx   = lane & 15, lg = lane >> 4;
    const int wm   = w >> 1, wn = w & 1;

    int gid = blockIdx.x;
    int nid = (gid & 7) * 64 + (gid >> 3);
    const int colBase = (nid & 7) * 128;
    const int rowBase = (nid >> 3) * 64;

    const int sRow = (lane >> 2);
    const int sChk = (lane & 3) ^ ((lane >> 2) & 3);

    auto STAGE = [&](int buf, int k0) {
        char* base = smem + buf * 12288;
        gload16(Ap + (size_t)(rowBase + w * 16 + sRow) * D_ + k0 + sChk * 8,
                base + w * 1024);
        #pragma unroll
        for (int ii = 0; ii < 2; ++ii) {
            int i = w * 2 + ii;
            int r = i * 16 + sRow;
            gload16(Bhi + (size_t)(colBase + r) * D_ + k0 + sChk * 8,
                    base + 4096 + i * 1024);
        }
    };

    f32x4 acc[2][4];
    #pragma unroll
    for (int i = 0; i < 2; ++i)
        #pragma unroll
        for (int j = 0; j < 4; ++j) acc[i][j] = (f32x4){0.f, 0.f, 0.f, 0.f};

    STAGE(0, 0);
    __syncthreads();
    int cur = 0;
    for (int k0 = 0; k0 < D_; k0 += 32) {
        if (k0 + 32 < D_) STAGE(cur ^ 1, k0 + 32);
        char* base = smem + cur * 12288;
        _Float16* AS = (_Float16*)base;
        _Float16* BS = (_Float16*)(base + 4096);

        f16x8 bh[4];
        #pragma unroll
        for (int fj = 0; fj < 4; ++fj) {
            int brow = wn * 64 + fj * 16 + lx;
            bh[fj] = *(const f16x8*)((char*)BS + brow * 64 + 16 * (lg ^ (brow & 3)));
        }
        #pragma unroll
        for (int fi = 0; fi < 2; ++fi) {
            int arow = wm * 32 + fi * 16 + lx;
            f16x8 ah = *(const f16x8*)((char*)AS + arow * 64 + 16 * (lg ^ (arow & 3)));
            #pragma unroll
            for (int fj = 0; fj < 4; ++fj)
                acc[fi][fj] = MFMA16(ah, bh[fj], acc[fi][fj]);
        }
        __syncthreads();
        cur ^= 1;
    }

    constexpr float INV = 1.f / 64.f;
    #pragma unroll
    for (int fi = 0; fi < 2; ++fi) {
        #pragma unroll
        for (int fj = 0; fj < 4; ++fj) {
            int n = colBase + wn * 64 + fj * 16 + lx;
            float bv = bias[n];
            #pragma unroll
            for (int rr = 0; rr < 4; ++rr) {
                int m = rowBase + wm * 32 + fi * 16 + lg * 4 + rr;
                out[(size_t)m * D_ + n] = acc[fi][fj][rr] * INV + bv;
            }
        }
    }
}

// ---------------- flash v9b: P in-register, consumer-side ct select -----------
// Target lane (lx,lg) slot m needs pk[ct][m&1] from lane lx+32b(+16), where
// ct = CONSUMER's a = lg>>1 (pa0: ct=a; pa1: ct=2+a).  One shfl publishes one
// producer value, and consumers lg and lg+2 of the same producer need different
// ct -> shuffle BOTH ct candidates, select after with own a.  16 shfl + 8 sel.
__global__ __launch_bounds__(512, 4)
void flash_mfma(const _Float16* __restrict__ Qhi, const _Float16* __restrict__ Qlo,
                const _Float16* __restrict__ Khi, const _Float16* __restrict__ Klo,
                const _Float16* __restrict__ Vt, const unsigned long long* __restrict__ Mb,
                _Float16* __restrict__ octx)
{
    __shared__ __attribute__((aligned(16))) _Float16 Kbuf[2][2][64 * 64]; // 32 KB
    __shared__ __attribute__((aligned(16))) _Float16 Vbuf[2][64 * 64];    // 16 KB

    const int tid  = threadIdx.x;
    const int lane = tid & 63;
    const int w    = tid >> 6;
    const int lx   = lane & 15;
    const int lg   = lane >> 4;

    int bid = blockIdx.x;
    int swz = (bid & 7) * 64 + (bid >> 3);
    int qb = swz & 15;
    int h  = (swz >> 4) & 15;
    int b  = swz >> 8;

    const int q0 = qb * 128;
    const size_t bh = (size_t)b * H_ + h;
    const _Float16* KhiG = Khi + bh * S_ * DK_;
    const _Float16* KloG = Klo + bh * S_ * DK_;
    const _Float16* VtG  = Vt  + bh * DK_ * S_;

    const int qrow = q0 + w * 16 + lx;
    f16x8 qh[2], ql[2];
    {
        const _Float16* ph = Qhi + bh * S_ * DK_ + (size_t)qrow * DK_ + lg * 8;
        const _Float16* pl = Qlo + bh * S_ * DK_ + (size_t)qrow * DK_ + lg * 8;
        qh[0] = *(const f16x8*)ph;
        qh[1] = *(const f16x8*)(ph + 32);
        ql[0] = *(const f16x8*)pl;
        ql[1] = *(const f16x8*)(pl + 32);
    }

    const unsigned long long* mrow = Mb + ((size_t)b * S_ + qrow) * (S_ / 64);
    constexpr float LN8 = 2.0794415416798357f;

    // loop-invariant bpermute source lanes: addr0 = lx + 32*(lg&1), addr1 = +16
    const int addr0 = (lane & 15) | ((lane & 16) << 1);
    const int addr1 = addr0 + 16;
    const bool ahi = (lane & 32) != 0;     // consumer's a = lg>>1

    auto STAGE = [&](int buf, int t) {
        int rr = w * 8 + (lane >> 3);
        int cc = (lane & 7) ^ (lane >> 3);
        gload16(KhiG + (size_t)(t * 64 + rr) * DK_ + cc * 8, &Kbuf[buf][0][w * 512]);
        gload16(KloG + (size_t)(t * 64 + rr) * DK_ + cc * 8, &Kbuf[buf][1][w * 512]);
        gload16(VtG + (size_t)rr * S_ + t * 64 + cc * 8, &Vbuf[buf][w * 512]);
    };

    f32x4 oacc[4];
    float m_run = -1e30f, l_lane = 0.f;
    #pragma unroll
    for (int dt = 0; dt < 4; ++dt) oacc[dt] = (f32x4){0.f, 0.f, 0.f, 0.f};

    auto TILE = [&](int t, const char* KH, const char* KL, const char* VB) {
        unsigned long long mw = mrow[t];
        unsigned mlo = (unsigned)(mw >> (lg * 4));         // ct 0,1 bits
        unsigned mhi = (unsigned)(mw >> 32) >> (lg * 4);   // ct 2,3 bits

        float sv[16];
        __builtin_amdgcn_s_setprio(1);
        #pragma unroll
        for (int ct = 0; ct < 4; ++ct) {
            int row  = ct * 16 + lx;
            int sw   = (row & 7) << 4;
            int base = row * 128 + lg * 16;
            f16x8 kh0 = *(const f16x8*)(KH + ((base +  0) ^ sw));
            f16x8 kh1 = *(const f16x8*)(KH + ((base + 64) ^ sw));
            f16x8 kl0 = *(const f16x8*)(KL + ((base +  0) ^ sw));
            f16x8 kl1 = *(const f16x8*)(KL + ((base + 64) ^ sw));
            f32x4 s = (f32x4){0.f, 0.f, 0.f, 0.f};
            s = MFMA16(kh0, qh[0], s);
            s = MFMA16(kh1, qh[1], s);
            s = MFMA16(kl0, qh[0], s);
            s = MFMA16(kl1, qh[1], s);
            s = MFMA16(kh0, ql[0], s);
            s = MFMA16(kh1, ql[1], s);
            unsigned mm = (ct < 2) ? mlo : mhi;
            int sh0 = (ct & 1) * 16;
            #pragma unroll
            for (int r = 0; r < 4; ++r)
                sv[ct * 4 + r] = ((mm >> (sh0 + r)) & 1u) ? s[r] : -1e30f;
        }
        __builtin_amdgcn_s_setprio(0);

        // masked row max (s-domain)
        float mx = fmaxf(fmaxf(fmaxf(sv[0], sv[1]), fmaxf(sv[2], sv[3])),
                         fmaxf(fmaxf(sv[4], sv[5]), fmaxf(sv[6], sv[7])));
        mx = fmaxf(mx, fmaxf(fmaxf(fmaxf(sv[8], sv[9]), fmaxf(sv[10], sv[11])),
                             fmaxf(fmaxf(sv[12], sv[13]), fmaxf(sv[14], sv[15]))));
        mx = fmaxf(mx, __shfl_xor(mx, 16));
        mx = fmaxf(mx, __shfl_xor(mx, 32));
        float tvmax = __expf(mx - LN8);

        if (__any(tvmax > m_run)) {
            float mn = fmaxf(m_run, tvmax);
            float scl = __expf(m_run - mn);
            m_run = mn;
            l_lane *= scl;
            #pragma unroll
            for (int dt = 0; dt < 4; ++dt)
                #pragma unroll
                for (int r = 0; r < 4; ++r) oacc[dt][r] *= scl;
        }

        float cut = (m_run >= 26.f) ? __logf(m_run - 25.f) + LN8 : -1e29f;
        if (__all(mx < cut)) return;         // whole tile dead

        float mr = m_run;
        float pp[16];
        #pragma unroll
        for (int i = 0; i < 16; ++i) {
            float e = 0.f;
            if (__any(sv[i] > cut)) {
                float tv = __expf(sv[i] - LN8);
                e = __expf(tv - mr);
                e = (sv[i] > cut) ? e : 0.f;
                l_lane += e;
            }
            pp[i] = e;
        }

        // ---- pack P pairs (adjacent k within ct): pk[ct][half]
        unsigned pk00, pk01, pk10, pk11, pk20, pk21, pk30, pk31;
        {
            fp16x2 v;
            v = __builtin_amdgcn_cvt_pkrtz(pp[ 0], pp[ 1]); __builtin_memcpy(&pk00, &v, 4);
            v = __builtin_amdgcn_cvt_pkrtz(pp[ 2], pp[ 3]); __builtin_memcpy(&pk01, &v, 4);
            v = __builtin_amdgcn_cvt_pkrtz(pp[ 4], pp[ 5]); __builtin_memcpy(&pk10, &v, 4);
            v = __builtin_amdgcn_cvt_pkrtz(pp[ 6], pp[ 7]); __builtin_memcpy(&pk11, &v, 4);
            v = __builtin_amdgcn_cvt_pkrtz(pp[ 8], pp[ 9]); __builtin_memcpy(&pk20, &v, 4);
            v = __builtin_amdgcn_cvt_pkrtz(pp[10], pp[11]); __builtin_memcpy(&pk21, &v, 4);
            v = __builtin_amdgcn_cvt_pkrtz(pp[12], pp[13]); __builtin_memcpy(&pk30, &v, 4);
            v = __builtin_amdgcn_cvt_pkrtz(pp[14], pp[15]); __builtin_memcpy(&pk31, &v, 4);
        }
        // ---- shuffle both ct candidates; select with CONSUMER's a
        unsigned t00a = __shfl(pk00, addr0, 64), t10a = __shfl(pk10, addr0, 64);
        unsigned t01a = __shfl(pk01, addr0, 64), t11a = __shfl(pk11, addr0, 64);
        unsigned t00b = __shfl(pk00, addr1, 64), t10b = __shfl(pk10, addr1, 64);
        unsigned t01b = __shfl(pk01, addr1, 64), t11b = __shfl(pk11, addr1, 64);
        unsigned t20a = __shfl(pk20, addr0, 64), t30a = __shfl(pk30, addr0, 64);
        unsigned t21a = __shfl(pk21, addr0, 64), t31a = __shfl(pk31, addr0, 64);
        unsigned t20b = __shfl(pk20, addr1, 64), t30b = __shfl(pk30, addr1, 64);
        unsigned t21b = __shfl(pk21, addr1, 64), t31b = __shfl(pk31, addr1, 64);
        u32x4 pa0u, pa1u;
        pa0u[0] = ahi ? t10a : t00a;
        pa0u[1] = ahi ? t11a : t01a;
        pa0u[2] = ahi ? t10b : t00b;
        pa0u[3] = ahi ? t11b : t01b;
        pa1u[0] = ahi ? t30a : t20a;
        pa1u[1] = ahi ? t31a : t21a;
        pa1u[2] = ahi ? t30b : t20b;
        pa1u[3] = ahi ? t31b : t21b;
        f16x8 pa0, pa1;
        __builtin_memcpy(&pa0, &pa0u, 16);
        __builtin_memcpy(&pa1, &pa1u, 16);

        __builtin_amdgcn_s_setprio(1);
        #pragma unroll
        for (int dt = 0; dt < 4; ++dt) {
            int vrow = dt * 16 + lx;
            int vs   = (vrow & 7) << 4;
            int vb   = vrow * 128 + lg * 16;
            f16x8 v0 = *(const f16x8*)(VB + ((vb +  0) ^ vs));
            f16x8 v1 = *(const f16x8*)(VB + ((vb + 64) ^ vs));
            oacc[dt] = MFMA16(v0, pa0, oacc[dt]);
            oacc[dt] = MFMA16(v1, pa1, oacc[dt]);
        }
        __builtin_amdgcn_s_setprio(0);
    };

    STAGE(0, 0);
    #pragma unroll 1
    for (int t = 0; t < 32; t += 2) {
        __syncthreads();                 // buf0 ready; prior buf0 reads done
        STAGE(1, t + 1);
        TILE(t, (const char*)&Kbuf[0][0][0], (const char*)&Kbuf[0][1][0],
             (const char*)&Vbuf[0][0]);
        __syncthreads();                 // buf1 ready; buf0 reads done
        if (t + 2 < 32) STAGE(0, t + 2);
        TILE(t + 1, (const char*)&Kbuf[1][0][0], (const char*)&Kbuf[1][1][0],
             (const char*)&Vbuf[1][0]);
    }

    float l = l_lane;
    l += __shfl_xor(l, 16);
    l += __shfl_xor(l, 32);
    {
        float inv = 1.0f / l;
        #pragma unroll
        for (int dt = 0; dt < 4; ++dt) {
            f16x4 o;
            #pragma unroll
            for (int r = 0; r < 4; ++r) o[r] = (_Float16)(oacc[dt][r] * inv);
            *(f16x4*)&octx[((size_t)b * S_ + qrow) * D_ + h * DK_ + dt * 16 + lg * 4] = o;
        }
    }
}

extern "C" void kernel_launch(void* const* d_in, const int* in_sizes, int n_in,
                              void* d_out, int out_size, void* d_ws, size_t ws_size,
                              hipStream_t stream)
{
    const float* query = (const float*)d_in[0];
    const float* key_  = (const float*)d_in[1];
    const float* value = (const float*)d_in[2];
    const int*   mask  = (const int*)d_in[3];
    const float* Wq = (const float*)d_in[4];
    const float* bq = (const float*)d_in[5];
    const float* Wk = (const float*)d_in[6];
    const float* bk = (const float*)d_in[7];
    const float* Wv = (const float*)d_in[8];
    const float* bv = (const float*)d_in[9];
    const float* Wo = (const float*)d_in[10];
    const float* bo = (const float*)d_in[11];

    char* p = (char*)d_ws;
    unsigned long long* mbits = (unsigned long long*)p;  p += (size_t)1 << 20;
    _Float16* WhiQ = (_Float16*)p;  p += (size_t)2 << 20;
    _Float16* WloQ = (_Float16*)p;  p += (size_t)2 << 20;
    _Float16* WhiK = (_Float16*)p;  p += (size_t)2 << 20;
    _Float16* WloK = (_Float16*)p;  p += (size_t)2 << 20;
    _Float16* WhiV = (_Float16*)p;  p += (size_t)2 << 20;
    _Float16* WhiO = (_Float16*)p;  p += (size_t)2 << 20;
    _Float16* Xhq  = (_Float16*)p;  p += (size_t)8 << 20;
    _Float16* Xlq  = (_Float16*)p;  p += (size_t)8 << 20;
    _Float16* Xhk  = (_Float16*)p;  p += (size_t)8 << 20;
    _Float16* Xlk  = (_Float16*)p;  p += (size_t)8 << 20;
    _Float16* Xhv  = (_Float16*)p;  p += (size_t)8 << 20;
    _Float16* Qhi  = (_Float16*)p;  p += (size_t)16 << 20;  // lo at +M_*D_
    _Float16* Khi  = (_Float16*)p;  p += (size_t)16 << 20;  // lo at +M_*D_
    _Float16* VtW  = (_Float16*)p;  p += (size_t)8 << 20;
    _Float16* octx = (_Float16*)p;  p += (size_t)8 << 20;
    float* out = (float*)d_out;

    _Float16* Qlo = Qhi + (size_t)M_ * D_;
    _Float16* Klo = Khi + (size_t)M_ * D_;

    // X+W split (8192 blocks) + maskpack (32768 blocks) fused
    splitmask<<<8192 + 32768, 256, 0, stream>>>(query, key_, value,
                                                Wq, Wk, Wv, Wo, mask, mbits,
                                                Xhq, Xlq, Xhk, Xlk, Xhv,
                                                WhiQ, WloQ, WhiK, WloK, WhiV, WhiO);

    proj3<<<768, 256, 65536, stream>>>(Xhq, Xlq, Xhk, Xlk, Xhv,
                                       WhiQ, WloQ, WhiK, WloK, WhiV,
                                       bq, bk, bv, Qhi, Khi, VtW);

    flash_mfma<<<512, 512, 0, stream>>>(Qhi, Qlo, Khi, Klo, VtW, mbits, octx);

    gemm64<<<512, 256, 0, stream>>>(octx, WhiO, bo, out);
}

// Round 19
// 190.933 us; speedup vs baseline: 1.0362x; 1.0362x over previous
//
#include <hip/hip_runtime.h>
#include <math.h>

#define B_ 2
#define S_ 2048
#define D_ 1024
#define H_ 16
#define DK_ 64
#define M_ (B_*S_)   // 4096

typedef __attribute__((ext_vector_type(8))) _Float16 f16x8;
typedef __attribute__((ext_vector_type(4))) _Float16 f16x4;
typedef __attribute__((ext_vector_type(2))) __fp16 fp16x2;
typedef __attribute__((ext_vector_type(4))) float f32x4;

#define MFMA16(a,b,c) __builtin_amdgcn_mfma_f32_16x16x32_f16((a),(b),(c),0,0,0)

__device__ __forceinline__ void gload16(const void* g, void* l) {
    __builtin_amdgcn_global_load_lds(
        (const __attribute__((address_space(1))) unsigned int*)g,
        (__attribute__((address_space(3))) unsigned int*)l, 16, 0, 0);
}

// ---- X+W split (blocks 0..8191) + mask bit-pack (blocks 8192..16383) ---------
__global__ __launch_bounds__(256)
void splitmask(const float* __restrict__ query, const float* __restrict__ key_,
               const float* __restrict__ value,
               const float* __restrict__ Wq, const float* __restrict__ Wk,
               const float* __restrict__ Wv, const float* __restrict__ Wo,
               const int* __restrict__ mask, unsigned long long* __restrict__ mbits,
               _Float16* __restrict__ Xhq, _Float16* __restrict__ Xlq,
               _Float16* __restrict__ Xhk, _Float16* __restrict__ Xlk,
               _Float16* __restrict__ Xhv,
               _Float16* __restrict__ hq, _Float16* __restrict__ lq,
               _Float16* __restrict__ hk, _Float16* __restrict__ lk,
               _Float16* __restrict__ hv, _Float16* __restrict__ ho)
{
    if (blockIdx.x >= 8192) {
        // 4 waves/block, each wave packs 4 consecutive u64 words
        int wid0 = ((blockIdx.x - 8192) * 4 + (threadIdx.x >> 6)) * 4;
        int lane = threadIdx.x & 63;
        #pragma unroll
        for (int j = 0; j < 4; ++j) {
            int v = mask[(size_t)(wid0 + j) * 64 + lane];
            unsigned long long bal = __ballot(v != 0);
            if (lane == 0) mbits[wid0 + j] = bal;
        }
        return;
    }
    int t = blockIdx.x * 256 + threadIdx.x;   // 2M threads, 8 elems each
    int region = t >> 19;                     // 0=q 1=k 2=v 3=weights
    int u = t & 524287;
    const float* src; _Float16* dhi; _Float16* dlo; size_t e;
    if (region < 3) {
        e = (size_t)u * 8;
        src = (region == 0) ? query : (region == 1) ? key_ : value;
        dhi = (region == 0) ? Xhq : (region == 1) ? Xhk : Xhv;
        dlo = (region == 0) ? Xlq : (region == 1) ? Xlk : nullptr;
    } else {
        int mi = u >> 17;
        e = (size_t)(u & 131071) * 8;
        src = (mi == 0) ? Wq : (mi == 1) ? Wk : (mi == 2) ? Wv : Wo;
        dhi = (mi == 0) ? hq : (mi == 1) ? hk : (mi == 2) ? hv : ho;
        dlo = (mi == 0) ? lq : (mi == 1) ? lk : nullptr;
    }
    float4 a = *(const float4*)&src[e];
    float4 b = *(const float4*)&src[e + 4];
    float v[8] = {a.x, a.y, a.z, a.w, b.x, b.y, b.z, b.w};
    f16x8 hi, lo;
    #pragma unroll
    for (int j = 0; j < 8; ++j) {
        float s = v[j] * 64.f;                // pow2 scale keeps lo out of denorms
        _Float16 h = (_Float16)s;
        hi[j] = h; lo[j] = (_Float16)(s - (float)h);
    }
    *(f16x8*)&dhi[e] = hi;
    if (dlo) *(f16x8*)&dlo[e] = lo;
}

// ---------------- GEMM body: dbuf prefetch, all-gload16 staging ---------------
template<int NPROD, int OUT_MODE>
__device__ __forceinline__
void gemm_body2(char* smem, const _Float16* __restrict__ Ah,
                const _Float16* __restrict__ Al,
                const _Float16* __restrict__ Bh, const _Float16* __restrict__ Bl,
                const float* __restrict__ bias, void* __restrict__ outp, int gid)
{
    constexpr int BUFSZ = (NPROD == 3) ? 32768 : 16384;
    const int tid  = threadIdx.x;
    const int lane = tid & 63, w = tid >> 6;
    const int lx   = lane & 15, lg = lane >> 4;
    const int wm   = w >> 1, wn = w & 1;

    int nid = (gid & 7) * 32 + (gid >> 3);    // XCD-chunked swizzle
    const int colBase = (nid & 7) * 128;
    const int rowBase = (nid >> 3) * 128;

    const int sRow = (lane >> 2);
    const int sChk = (lane & 3) ^ ((lane >> 2) & 3);

    auto STAGE = [&](int buf, int k0) {
        char* base = smem + buf * BUFSZ;
        #pragma unroll
        for (int ii = 0; ii < 2; ++ii) {
            int i = w * 2 + ii;
            int r = i * 16 + sRow;
            gload16(Ah + (size_t)(rowBase + r) * D_ + k0 + sChk * 8, base + i * 1024);
            gload16(Bh + (size_t)(colBase + r) * D_ + k0 + sChk * 8, base + 8192 + i * 1024);
            if (NPROD == 3) {
                gload16(Al + (size_t)(rowBase + r) * D_ + k0 + sChk * 8, base + 16384 + i * 1024);
                gload16(Bl + (size_t)(colBase + r) * D_ + k0 + sChk * 8, base + 24576 + i * 1024);
            }
        }
    };

    f32x4 acc[4][4];
    #pragma unroll
    for (int i = 0; i < 4; ++i)
        #pragma unroll
        for (int j = 0; j < 4; ++j) acc[i][j] = (f32x4){0.f, 0.f, 0.f, 0.f};

    STAGE(0, 0);
    __syncthreads();
    int cur = 0;
    for (int k0 = 0; k0 < D_; k0 += 32) {
        if (k0 + 32 < D_) STAGE(cur ^ 1, k0 + 32);
        char* base = smem + cur * BUFSZ;
        _Float16* AhS = (_Float16*)base;
        _Float16* BhS = (_Float16*)(base + 8192);
        _Float16* AlS = (_Float16*)(base + 16384);
        _Float16* BlS = (_Float16*)(base + 24576);

        f16x8 bh[4], bl[4];
        #pragma unroll
        for (int fj = 0; fj < 4; ++fj) {
            int brow = wn * 64 + fj * 16 + lx;
            bh[fj] = *(const f16x8*)((char*)BhS + brow * 64 + 16 * (lg ^ (brow & 3)));
            if (NPROD == 3)
                bl[fj] = *(const f16x8*)((char*)BlS + brow * 64 + 16 * (lg ^ (brow & 3)));
        }
        #pragma unroll
        for (int fi = 0; fi < 4; ++fi) {
            int arow = wm * 64 + fi * 16 + lx;
            f16x8 ah = *(const f16x8*)((char*)AhS + arow * 64 + 16 * (lg ^ (arow & 3)));
            f16x8 al;
            if (NPROD == 3)
                al = *(const f16x8*)((char*)AlS + arow * 64 + 16 * (lg ^ (arow & 3)));
            #pragma unroll
            for (int fj = 0; fj < 4; ++fj) {
                acc[fi][fj] = MFMA16(ah, bh[fj], acc[fi][fj]);
                if (NPROD == 3) {
                    acc[fi][fj] = MFMA16(ah, bl[fj], acc[fi][fj]);
                    acc[fi][fj] = MFMA16(al, bh[fj], acc[fi][fj]);
                }
            }
        }
        __syncthreads();
        cur ^= 1;
    }

    constexpr float INV = 1.f / 4096.f;
    #pragma unroll
    for (int fi = 0; fi < 4; ++fi) {
        #pragma unroll
        for (int fj = 0; fj < 4; ++fj) {
            int n = colBase + wn * 64 + fj * 16 + lx;
            float bv = bias[n];
            if (OUT_MODE == 1) {
                _Float16* Ohi = (_Float16*)outp;
                _Float16* Olo = Ohi + (size_t)M_ * D_;
                int hh = n >> 6, d = n & 63;
                #pragma unroll
                for (int rr = 0; rr < 4; ++rr) {
                    int m = rowBase + wm * 64 + fi * 16 + lg * 4 + rr;
                    int bb = m >> 11, s = m & 2047;
                    float val = acc[fi][fj][rr] * INV + bv;
                    _Float16 hv = (_Float16)val;
                    size_t o = (((size_t)bb * H_ + hh) * S_ + s) * DK_ + d;
                    Ohi[o] = hv;
                    Olo[o] = (_Float16)(val - (float)hv);
                }
            } else {
                _Float16* Vt = (_Float16*)outp;
                int hh = n >> 6, d = n & 63;
                int m0 = rowBase + wm * 64 + fi * 16 + lg * 4;
                int bb = m0 >> 11, s = m0 & 2047;
                f16x4 pk;
                #pragma unroll
                for (int rr = 0; rr < 4; ++rr)
                    pk[rr] = (_Float16)(acc[fi][fj][rr] * INV + bv);
                *(f16x4*)&Vt[(((size_t)bb * H_ + hh) * DK_ + d) * S_ + s] = pk;
            }
        }
    }
}

// ---------------- merged Q/K/V projection: 768 blocks --------------------------
__global__ __launch_bounds__(256)
void proj3(const _Float16* __restrict__ Xhq, const _Float16* __restrict__ Xlq,
           const _Float16* __restrict__ Xhk, const _Float16* __restrict__ Xlk,
           const _Float16* __restrict__ Xhv,
           const _Float16* __restrict__ WhiQ, const _Float16* __restrict__ WloQ,
           const _Float16* __restrict__ WhiK, const _Float16* __restrict__ WloK,
           const _Float16* __restrict__ WhiV,
           const float* __restrict__ bq, const float* __restrict__ bk,
           const float* __restrict__ bv,
           _Float16* __restrict__ Qhi, _Float16* __restrict__ Khi,
           _Float16* __restrict__ VtW)
{
    extern __shared__ char smem[];
    int mode = blockIdx.x >> 8;
    int gid  = blockIdx.x & 255;
    if (mode == 0)
        gemm_body2<3, 1>(smem, Xhq, Xlq, WhiQ, WloQ, bq, Qhi, gid);
    else if (mode == 1)
        gemm_body2<3, 1>(smem, Xhk, Xlk, WhiK, WloK, bk, Khi, gid);
    else
        gemm_body2<1, 2>(smem, Xhv, nullptr, WhiV, nullptr, bv, VtW, gid);
}

// ---------------- O-proj GEMM: 64x128 tile, dbuf gload16 both operands --------
__global__ __launch_bounds__(256)
void gemm64(const _Float16* __restrict__ Ap, const _Float16* __restrict__ Bhi,
            const float* __restrict__ bias, float* __restrict__ out)
{
    __shared__ __attribute__((aligned(16))) char smem[24576];

    const int tid  = threadIdx.x;
    const int lane = tid & 63, w = tid >> 6;
    const int lx   = lane & 15, lg = lane >> 4;
    const int wm   = w >> 1, wn = w & 1;

    int gid = blockIdx.x;
    int nid = (gid & 7) * 64 + (gid >> 3);
    const int colBase = (nid & 7) * 128;
    const int rowBase = (nid >> 3) * 64;

    const int sRow = (lane >> 2);
    const int sChk = (lane & 3) ^ ((lane >> 2) & 3);

    auto STAGE = [&](int buf, int k0) {
        char* base = smem + buf * 12288;
        gload16(Ap + (size_t)(rowBase + w * 16 + sRow) * D_ + k0 + sChk * 8,
                base + w * 1024);
        #pragma unroll
        for (int ii = 0; ii < 2; ++ii) {
            int i = w * 2 + ii;
            int r = i * 16 + sRow;
            gload16(Bhi + (size_t)(colBase + r) * D_ + k0 + sChk * 8,
                    base + 4096 + i * 1024);
        }
    };

    f32x4 acc[2][4];
    #pragma unroll
    for (int i = 0; i < 2; ++i)
        #pragma unroll
        for (int j = 0; j < 4; ++j) acc[i][j] = (f32x4){0.f, 0.f, 0.f, 0.f};

    STAGE(0, 0);
    __syncthreads();
    int cur = 0;
    for (int k0 = 0; k0 < D_; k0 += 32) {
        if (k0 + 32 < D_) STAGE(cur ^ 1, k0 + 32);
        char* base = smem + cur * 12288;
        _Float16* AS = (_Float16*)base;
        _Float16* BS = (_Float16*)(base + 4096);

        f16x8 bh[4];
        #pragma unroll
        for (int fj = 0; fj < 4; ++fj) {
            int brow = wn * 64 + fj * 16 + lx;
            bh[fj] = *(const f16x8*)((char*)BS + brow * 64 + 16 * (lg ^ (brow & 3)));
        }
        #pragma unroll
        for (int fi = 0; fi < 2; ++fi) {
            int arow = wm * 32 + fi * 16 + lx;
            f16x8 ah = *(const f16x8*)((char*)AS + arow * 64 + 16 * (lg ^ (arow & 3)));
            #pragma unroll
            for (int fj = 0; fj < 4; ++fj)
                acc[fi][fj] = MFMA16(ah, bh[fj], acc[fi][fj]);
        }
        __syncthreads();
        cur ^= 1;
    }

    constexpr float INV = 1.f / 64.f;
    #pragma unroll
    for (int fi = 0; fi < 2; ++fi) {
        #pragma unroll
        for (int fj = 0; fj < 4; ++fj) {
            int n = colBase + wn * 64 + fj * 16 + lx;
            float bv = bias[n];
            #pragma unroll
            for (int rr = 0; rr < 4; ++rr) {
                int m = rowBase + wm * 32 + fi * 16 + lg * 4 + rr;
                out[(size_t)m * D_ + n] = acc[fi][fj][rr] * INV + bv;
            }
        }
    }
}

// ---------------- flash v8 (round-16 proven 98.7us): P via per-wave LDS -------
__global__ __launch_bounds__(512, 4)
void flash_mfma(const _Float16* __restrict__ Qhi, const _Float16* __restrict__ Qlo,
                const _Float16* __restrict__ Khi, const _Float16* __restrict__ Klo,
                const _Float16* __restrict__ Vt, const unsigned long long* __restrict__ Mb,
                _Float16* __restrict__ octx)
{
    __shared__ __attribute__((aligned(16))) _Float16 Kbuf[2][2][64 * 64]; // 32 KB
    __shared__ __attribute__((aligned(16))) _Float16 Vbuf[2][64 * 64];    // 16 KB
    __shared__ __attribute__((aligned(16))) _Float16 PwS[8][16 * 64];     // 16 KB

    const int tid  = threadIdx.x;
    const int lane = tid & 63;
    const int w    = tid >> 6;
    const int lx   = lane & 15;
    const int lg   = lane >> 4;

    int bid = blockIdx.x;
    int swz = (bid & 7) * 64 + (bid >> 3);
    int qb = swz & 15;
    int h  = (swz >> 4) & 15;
    int b  = swz >> 8;

    const int q0 = qb * 128;
    const size_t bh = (size_t)b * H_ + h;
    const _Float16* KhiG = Khi + bh * S_ * DK_;
    const _Float16* KloG = Klo + bh * S_ * DK_;
    const _Float16* VtG  = Vt  + bh * DK_ * S_;

    const int qrow = q0 + w * 16 + lx;
    f16x8 qh[2], ql[2];
    {
        const _Float16* ph = Qhi + bh * S_ * DK_ + (size_t)qrow * DK_ + lg * 8;
        const _Float16* pl = Qlo + bh * S_ * DK_ + (size_t)qrow * DK_ + lg * 8;
        qh[0] = *(const f16x8*)ph;
        qh[1] = *(const f16x8*)(ph + 32);
        ql[0] = *(const f16x8*)pl;
        ql[1] = *(const f16x8*)(pl + 32);
    }

    const unsigned long long* mrow = Mb + ((size_t)b * S_ + qrow) * (S_ / 64);
    constexpr float LN8 = 2.0794415416798357f;

    auto STAGE = [&](int buf, int t) {
        int rr = w * 8 + (lane >> 3);
        int cc = (lane & 7) ^ (lane >> 3);
        gload16(KhiG + (size_t)(t * 64 + rr) * DK_ + cc * 8, &Kbuf[buf][0][w * 512]);
        gload16(KloG + (size_t)(t * 64 + rr) * DK_ + cc * 8, &Kbuf[buf][1][w * 512]);
        gload16(VtG + (size_t)rr * S_ + t * 64 + cc * 8, &Vbuf[buf][w * 512]);
    };

    f32x4 oacc[4];
    float m_run = -1e30f, l_lane = 0.f;
    #pragma unroll
    for (int dt = 0; dt < 4; ++dt) oacc[dt] = (f32x4){0.f, 0.f, 0.f, 0.f};

    char* Pw = (char*)&PwS[w][0];

    auto TILE = [&](int t, const char* KH, const char* KL, const char* VB) {
        unsigned long long mw = mrow[t];
        unsigned mlo = (unsigned)(mw >> (lg * 4));         // ct 0,1 bits
        unsigned mhi = (unsigned)(mw >> 32) >> (lg * 4);   // ct 2,3 bits

        float sv[16];
        __builtin_amdgcn_s_setprio(1);
        #pragma unroll
        for (int ct = 0; ct < 4; ++ct) {
            int row  = ct * 16 + lx;
            int sw   = (row & 7) << 4;
            int base = row * 128 + lg * 16;
            f16x8 kh0 = *(const f16x8*)(KH + ((base +  0) ^ sw));
            f16x8 kh1 = *(const f16x8*)(KH + ((base + 64) ^ sw));
            f16x8 kl0 = *(const f16x8*)(KL + ((base +  0) ^ sw));
            f16x8 kl1 = *(const f16x8*)(KL + ((base + 64) ^ sw));
            f32x4 s = (f32x4){0.f, 0.f, 0.f, 0.f};
            s = MFMA16(kh0, qh[0], s);
            s = MFMA16(kh1, qh[1], s);
            s = MFMA16(kl0, qh[0], s);
            s = MFMA16(kl1, qh[1], s);
            s = MFMA16(kh0, ql[0], s);
            s = MFMA16(kh1, ql[1], s);
            unsigned mm = (ct < 2) ? mlo : mhi;
            int sh0 = (ct & 1) * 16;
            #pragma unroll
            for (int r = 0; r < 4; ++r)
                sv[ct * 4 + r] = ((mm >> (sh0 + r)) & 1u) ? s[r] : -1e30f;
        }
        __builtin_amdgcn_s_setprio(0);

        // masked row max (s-domain)
        float mx = fmaxf(fmaxf(fmaxf(sv[0], sv[1]), fmaxf(sv[2], sv[3])),
                         fmaxf(fmaxf(sv[4], sv[5]), fmaxf(sv[6], sv[7])));
        mx = fmaxf(mx, fmaxf(fmaxf(fmaxf(sv[8], sv[9]), fmaxf(sv[10], sv[11])),
                             fmaxf(fmaxf(sv[12], sv[13]), fmaxf(sv[14], sv[15]))));
        mx = fmaxf(mx, __shfl_xor(mx, 16));
        mx = fmaxf(mx, __shfl_xor(mx, 32));
        float tvmax = __expf(mx - LN8);

        if (__any(tvmax > m_run)) {
            float mn = fmaxf(m_run, tvmax);
            float scl = __expf(m_run - mn);
            m_run = mn;
            l_lane *= scl;
            #pragma unroll
            for (int dt = 0; dt < 4; ++dt)
                #pragma unroll
                for (int r = 0; r < 4; ++r) oacc[dt][r] *= scl;
        }

        float cut = (m_run >= 26.f) ? __logf(m_run - 25.f) + LN8 : -1e29f;
        if (__all(mx < cut)) return;         // whole tile dead

        float mr = m_run;
        float pp[16];
        #pragma unroll
        for (int i = 0; i < 16; ++i) {
            float e = 0.f;
            if (__any(sv[i] > cut)) {
                float tv = __expf(sv[i] - LN8);
                e = __expf(tv - mr);
                e = (sv[i] > cut) ? e : 0.f;
                l_lane += e;
            }
            pp[i] = e;
        }

        {
            int psw = (lx & 7) << 4;
            #pragma unroll
            for (int ct = 0; ct < 4; ++ct) {
                fp16x2 a = __builtin_amdgcn_cvt_pkrtz(pp[ct * 4 + 0], pp[ct * 4 + 1]);
                fp16x2 c = __builtin_amdgcn_cvt_pkrtz(pp[ct * 4 + 2], pp[ct * 4 + 3]);
                unsigned int au, cu;
                __builtin_memcpy(&au, &a, 4);
                __builtin_memcpy(&cu, &c, 4);
                int off = lx * 128 + ct * 32 + lg * 8;
                *(unsigned int*)(Pw + ((off + 0) ^ psw)) = au;
                *(unsigned int*)(Pw + ((off + 4) ^ psw)) = cu;
            }
        }

        f16x8 pa0, pa1;
        {
            int psw = (lx & 7) << 4;
            int pb  = lx * 128 + lg * 16;
            pa0 = *(const f16x8*)(Pw + ((pb +  0) ^ psw));
            pa1 = *(const f16x8*)(Pw + ((pb + 64) ^ psw));
        }
        __builtin_amdgcn_s_setprio(1);
        #pragma unroll
        for (int dt = 0; dt < 4; ++dt) {
            int vrow = dt * 16 + lx;
            int vs   = (vrow & 7) << 4;
            int vb   = vrow * 128 + lg * 16;
            f16x8 v0 = *(const f16x8*)(VB + ((vb +  0) ^ vs));
            f16x8 v1 = *(const f16x8*)(VB + ((vb + 64) ^ vs));
            oacc[dt] = MFMA16(v0, pa0, oacc[dt]);
            oacc[dt] = MFMA16(v1, pa1, oacc[dt]);
        }
        __builtin_amdgcn_s_setprio(0);
    };

    STAGE(0, 0);
    #pragma unroll 1
    for (int t = 0; t < 32; t += 2) {
        __syncthreads();                 // buf0 ready; prior buf0 reads done
        STAGE(1, t + 1);
        TILE(t, (const char*)&Kbuf[0][0][0], (const char*)&Kbuf[0][1][0],
             (const char*)&Vbuf[0][0]);
        __syncthreads();                 // buf1 ready; buf0 reads done
        if (t + 2 < 32) STAGE(0, t + 2);
        TILE(t + 1, (const char*)&Kbuf[1][0][0], (const char*)&Kbuf[1][1][0],
             (const char*)&Vbuf[1][0]);
    }

    float l = l_lane;
    l += __shfl_xor(l, 16);
    l += __shfl_xor(l, 32);
    {
        float inv = 1.0f / l;
        #pragma unroll
        for (int dt = 0; dt < 4; ++dt) {
            f16x4 o;
            #pragma unroll
            for (int r = 0; r < 4; ++r) o[r] = (_Float16)(oacc[dt][r] * inv);
            *(f16x4*)&octx[((size_t)b * S_ + qrow) * D_ + h * DK_ + dt * 16 + lg * 4] = o;
        }
    }
}

extern "C" void kernel_launch(void* const* d_in, const int* in_sizes, int n_in,
                              void* d_out, int out_size, void* d_ws, size_t ws_size,
                              hipStream_t stream)
{
    const float* query = (const float*)d_in[0];
    const float* key_  = (const float*)d_in[1];
    const float* value = (const float*)d_in[2];
    const int*   mask  = (const int*)d_in[3];
    const float* Wq = (const float*)d_in[4];
    const float* bq = (const float*)d_in[5];
    const float* Wk = (const float*)d_in[6];
    const float* bk = (const float*)d_in[7];
    const float* Wv = (const float*)d_in[8];
    const float* bv = (const float*)d_in[9];
    const float* Wo = (const float*)d_in[10];
    const float* bo = (const float*)d_in[11];

    char* p = (char*)d_ws;
    unsigned long long* mbits = (unsigned long long*)p;  p += (size_t)1 << 20;
    _Float16* WhiQ = (_Float16*)p;  p += (size_t)2 << 20;
    _Float16* WloQ = (_Float16*)p;  p += (size_t)2 << 20;
    _Float16* WhiK = (_Float16*)p;  p += (size_t)2 << 20;
    _Float16* WloK = (_Float16*)p;  p += (size_t)2 << 20;
    _Float16* WhiV = (_Float16*)p;  p += (size_t)2 << 20;
    _Float16* WhiO = (_Float16*)p;  p += (size_t)2 << 20;
    _Float16* Xhq  = (_Float16*)p;  p += (size_t)8 << 20;
    _Float16* Xlq  = (_Float16*)p;  p += (size_t)8 << 20;
    _Float16* Xhk  = (_Float16*)p;  p += (size_t)8 << 20;
    _Float16* Xlk  = (_Float16*)p;  p += (size_t)8 << 20;
    _Float16* Xhv  = (_Float16*)p;  p += (size_t)8 << 20;
    _Float16* Qhi  = (_Float16*)p;  p += (size_t)16 << 20;  // lo at +M_*D_
    _Float16* Khi  = (_Float16*)p;  p += (size_t)16 << 20;  // lo at +M_*D_
    _Float16* VtW  = (_Float16*)p;  p += (size_t)8 << 20;
    _Float16* octx = (_Float16*)p;  p += (size_t)8 << 20;
    float* out = (float*)d_out;

    _Float16* Qlo = Qhi + (size_t)M_ * D_;
    _Float16* Klo = Khi + (size_t)M_ * D_;

    // X+W split (8192 blocks) + maskpack (8192 blocks, 4 words/wave) fused
    splitmask<<<8192 + 8192, 256, 0, stream>>>(query, key_, value,
                                               Wq, Wk, Wv, Wo, mask, mbits,
                                               Xhq, Xlq, Xhk, Xlk, Xhv,
                                               WhiQ, WloQ, WhiK, WloK, WhiV, WhiO);

    proj3<<<768, 256, 65536, stream>>>(Xhq, Xlq, Xhk, Xlk, Xhv,
                                       WhiQ, WloQ, WhiK, WloK, WhiV,
                                       bq, bk, bv, Qhi, Khi, VtW);

    flash_mfma<<<512, 512, 0, stream>>>(Qhi, Qlo, Khi, Klo, VtW, mbits, octx);

    gemm64<<<512, 256, 0, stream>>>(octx, WhiO, bo, out);
}